// Round 12
// baseline (94.899 us; speedup 1.0000x reference)
//
#include <hip/hip_runtime.h>
#include <hip/hip_bf16.h>

// GATConv: N=50000, E=1.6M (row sorted), IN_C=128, HEADS=4, OUT_C=32 (H*C=128)
//   1) prep_kernel:  W -> Wt (bf16, transposed, 16B chunks, linear) + row_ptr scatter
//   2) gemm_kernel:  MFMA bf16 16x16x32, LDS-FREE: A fragments loaded direct from
//                    global (f32 -> bf16 in-reg, fully coalesced), B fragments from
//                    the 32KB wt (L1/L2-resident broadcast). No barriers, ~8 blk/CU.
//   3) agg_kernel:   FROZEN r10: 1 wave/node, max-free softmax, bf16-packed LDS
//                    weights, full-wave dword gather unroll 8, 8 blocks/CU.
// agg wall (r2-r10): ~171MB random-miss @ ~3.4TB/s; redesigns (r6 bucket, r7 pool,
// r8 XCD-slice) and gather-width changes (r3, r4) all regressed. Do not touch agg.
// r11 lesson: LDS-repack epilogue + rowptr-in-gemm both net-negative; reverted.

#define IN_C 128
#define HC 128
#define STG 256

typedef __attribute__((ext_vector_type(8))) __bf16 bfrag_t;
typedef __attribute__((ext_vector_type(4))) float f32x4;
union frag_u { uint4 u; bfrag_t b; };

static __device__ inline unsigned short f2bf(float f) {
    unsigned u = __float_as_uint(f);
    unsigned r = (u + 0x7fffu + ((u >> 16) & 1u)) >> 16;  // round-nearest-even
    return (unsigned short)r;
}
static __device__ inline unsigned pack2(float a, float b) {
    return (unsigned)f2bf(a) | ((unsigned)f2bf(b) << 16);
}
static __device__ inline float bf_lo(unsigned u) { return __uint_as_float(u << 16); }
static __device__ inline float bf_hi(unsigned u) { return __uint_as_float(u & 0xffff0000u); }

// fused: Wt prep (16384 items; NO swizzle -- no LDS consumer) + row_ptr scatter
__global__ __launch_bounds__(256) void prep_kernel(const float* __restrict__ W,
                                                   unsigned short* __restrict__ wt,
                                                   const int* __restrict__ row,
                                                   int* __restrict__ row_ptr,
                                                   int n_nodes, int E) {
    int gid = blockIdx.x * 256 + threadIdx.x;
    if (gid < IN_C * HC) {
        int n = gid >> 7, k = gid & 127;
        wt[((size_t)n * 16 + (k >> 3)) * 8 + (k & 7)] = f2bf(W[(size_t)k * HC + n]);
    }
    if (gid < E) {
        int lane = threadIdx.x & 63;
        int r1 = row[gid];
        int r0 = __shfl_up(r1, 1, 64);
        if (lane == 0) r0 = (gid == 0) ? -1 : row[gid - 1];
        for (int v = r0 + 1; v <= r1; ++v) row_ptr[v] = gid;
        if (gid == E - 1)
            for (int v = r1 + 1; v <= n_nodes; ++v) row_ptr[v] = E;
    }
}

// LDS-free MFMA GEMM: block = 64 rows (4 waves), wave w owns rows 16w..16w+15.
// A frag (16x16x32): lane(l15,q) holds x[arow][ks*32+8q .. +8) as bf16x8.
// B frag: lane(l15,q) holds Wt(n=16t+l15, chunk=ks*4+q) = W[k=8(4ks+q)..+8][n].
__global__ __launch_bounds__(256) void gemm_kernel(const float* __restrict__ x,
                                                   const uint4* __restrict__ wtv,
                                                   const float* __restrict__ attS,
                                                   const float* __restrict__ attD,
                                                   unsigned short* __restrict__ xp,
                                                   float* __restrict__ a_src,
                                                   float* __restrict__ a_dst, int n_nodes) {
    const int tid = threadIdx.x;
    const int base = blockIdx.x * 64;
    const int w = tid >> 6, l = tid & 63, l15 = l & 15, q = l >> 4;
    const int arow = base + 16 * w + l15;
    const bool arok = arow < n_nodes;
    const float* ap = x + (size_t)(arok ? arow : 0) * IN_C + 8 * q;

    f32x4 acc[8] = {};
    #pragma unroll
    for (int ks = 0; ks < 4; ++ks) {
        // A fragment: 8 consecutive f32 -> bf16x8 (zeros for OOB rows)
        frag_u a;
        if (arok) {
            float4 lo = *(const float4*)(ap + ks * 32);
            float4 hi = *(const float4*)(ap + ks * 32 + 4);
            a.u.x = pack2(lo.x, lo.y); a.u.y = pack2(lo.z, lo.w);
            a.u.z = pack2(hi.x, hi.y); a.u.w = pack2(hi.z, hi.w);
        } else {
            a.u = make_uint4(0u, 0u, 0u, 0u);
        }
        #pragma unroll
        for (int t = 0; t < 8; ++t) {
            frag_u b; b.u = wtv[(16 * t + l15) * 16 + ks * 4 + q];
            acc[t] = __builtin_amdgcn_mfma_f32_16x16x32_bf16(a.b, b.b, acc[t], 0, 0, 0);
        }
    }

    // epilogue (r10-proven): xp bf16 stores + att logits.
    // C-frag: col = 16t + l15, row = 16w + 4q + r; head(col) = t>>1.
    float avS[8], avD[8];
    #pragma unroll
    for (int t = 0; t < 8; ++t) {
        avS[t] = attS[16 * t + l15];
        avD[t] = attD[16 * t + l15];
    }
    float hpS[4][4] = {}, hpD[4][4] = {};
    #pragma unroll
    for (int t = 0; t < 8; ++t) {
        #pragma unroll
        for (int r = 0; r < 4; ++r) {
            float v = acc[t][r];
            hpS[r][t >> 1] = fmaf(v, avS[t], hpS[r][t >> 1]);
            hpD[r][t >> 1] = fmaf(v, avD[t], hpD[r][t >> 1]);
            int grow = base + 16 * w + 4 * q + r;
            if (grow < n_nodes)
                xp[(size_t)grow * HC + 16 * t + l15] = f2bf(v);
        }
    }
    #pragma unroll
    for (int r = 0; r < 4; ++r) {
        #pragma unroll
        for (int h = 0; h < 4; ++h) {
            #pragma unroll
            for (int off = 1; off < 16; off <<= 1) {
                hpS[r][h] += __shfl_xor(hpS[r][h], off, 64);
                hpD[r][h] += __shfl_xor(hpD[r][h], off, 64);
            }
        }
        int grow = base + 16 * w + 4 * q + r;
        if (l15 == 0 && grow < n_nodes) {
            *(float4*)(a_src + (size_t)grow * 4) =
                make_float4(hpS[r][0], hpS[r][1], hpS[r][2], hpS[r][3]);
            *(float4*)(a_dst + (size_t)grow * 4) =
                make_float4(hpD[r][0], hpD[r][1], hpD[r][2], hpD[r][3]);
        }
    }
}

// FROZEN r10 aggregation: bf16-packed LDS weights, 12.3KB LDS, 8 blocks/CU.
__global__ __launch_bounds__(256, 8) void agg_kernel(const unsigned* __restrict__ xp,
                                                     const float* __restrict__ a_src,
                                                     const float* __restrict__ a_dst,
                                                     const int* __restrict__ col,
                                                     const int* __restrict__ row_ptr,
                                                     const float* __restrict__ bias,
                                                     float* __restrict__ out, int n_nodes) {
    __shared__ uint2 lds_w[4][STG];
    __shared__ int   lds_c[4][STG];
    const int wid = threadIdx.x >> 6, lane = threadIdx.x & 63;
    const int n = blockIdx.x * 4 + wid;
    const bool alive = n < n_nodes;

    int start = 0, deg = 0;
    if (alive) { start = row_ptr[n]; deg = row_ptr[n + 1] - start; }
    const bool staged = deg <= STG;
    float4 as4 = alive ? *(const float4*)(a_src + (size_t)n * 4)
                       : make_float4(0.f, 0.f, 0.f, 0.f);

    float s0 = 0.f, s1 = 0.f, s2 = 0.f, s3 = 0.f;
    for (int i = lane; i < deg; i += 64) {
        int cc = col[start + i];
        float4 ad = *(const float4*)(a_dst + (size_t)cc * 4);
        float v0 = as4.x + ad.x, v1 = as4.y + ad.y, v2 = as4.z + ad.z, v3 = as4.w + ad.w;
        v0 = v0 > 0.f ? v0 : 0.2f * v0;  v1 = v1 > 0.f ? v1 : 0.2f * v1;
        v2 = v2 > 0.f ? v2 : 0.2f * v2;  v3 = v3 > 0.f ? v3 : 0.2f * v3;
        float w0 = __expf(v0), w1 = __expf(v1), w2 = __expf(v2), w3 = __expf(v3);
        if (staged) {
            lds_c[wid][i] = cc;
            lds_w[wid][i] = make_uint2(pack2(w0, w1), pack2(w2, w3));
        }
        s0 += w0; s1 += w1; s2 += w2; s3 += w3;
    }
    #pragma unroll
    for (int off = 1; off < 64; off <<= 1) {
        s0 += __shfl_xor(s0, off, 64);
        s1 += __shfl_xor(s1, off, 64);
        s2 += __shfl_xor(s2, off, 64);
        s3 += __shfl_xor(s3, off, 64);
    }

    const int h = lane >> 4;
    const float sh = h == 0 ? s0 : h == 1 ? s1 : h == 2 ? s2 : s3;
    const float inv = 1.0f / (sh + 1e-8f);
    const unsigned* xpl = xp + lane;
    float ac0 = 0.f, ac1 = 0.f;

    if (staged) {
        const uint2* wr = &lds_w[wid][0];
        const int*   cr = &lds_c[wid][0];
        int i = 0;
        for (; i + 8 <= deg; i += 8) {
            int c0 = cr[i+0], c1 = cr[i+1], c2 = cr[i+2], c3 = cr[i+3];
            int c4 = cr[i+4], c5 = cr[i+5], c6 = cr[i+6], c7 = cr[i+7];
            uint2 q0 = wr[i+0], q1 = wr[i+1], q2 = wr[i+2], q3 = wr[i+3];
            uint2 q4 = wr[i+4], q5 = wr[i+5], q6 = wr[i+6], q7 = wr[i+7];
            unsigned u0 = xpl[(size_t)c0 * 64];
            unsigned u1 = xpl[(size_t)c1 * 64];
            unsigned u2 = xpl[(size_t)c2 * 64];
            unsigned u3 = xpl[(size_t)c3 * 64];
            unsigned u4 = xpl[(size_t)c4 * 64];
            unsigned u5 = xpl[(size_t)c5 * 64];
            unsigned u6 = xpl[(size_t)c6 * 64];
            unsigned u7 = xpl[(size_t)c7 * 64];
            unsigned x0 = (h & 2) ? q0.y : q0.x;
            unsigned x1 = (h & 2) ? q1.y : q1.x;
            unsigned x2 = (h & 2) ? q2.y : q2.x;
            unsigned x3 = (h & 2) ? q3.y : q3.x;
            unsigned x4 = (h & 2) ? q4.y : q4.x;
            unsigned x5 = (h & 2) ? q5.y : q5.x;
            unsigned x6 = (h & 2) ? q6.y : q6.x;
            unsigned x7 = (h & 2) ? q7.y : q7.x;
            float w0 = (h & 1) ? bf_hi(x0) : bf_lo(x0);
            float w1 = (h & 1) ? bf_hi(x1) : bf_lo(x1);
            float w2 = (h & 1) ? bf_hi(x2) : bf_lo(x2);
            float w3 = (h & 1) ? bf_hi(x3) : bf_lo(x3);
            float w4 = (h & 1) ? bf_hi(x4) : bf_lo(x4);
            float w5 = (h & 1) ? bf_hi(x5) : bf_lo(x5);
            float w6 = (h & 1) ? bf_hi(x6) : bf_lo(x6);
            float w7 = (h & 1) ? bf_hi(x7) : bf_lo(x7);
            ac0 = fmaf(w0, bf_lo(u0), ac0);  ac1 = fmaf(w0, bf_hi(u0), ac1);
            ac0 = fmaf(w1, bf_lo(u1), ac0);  ac1 = fmaf(w1, bf_hi(u1), ac1);
            ac0 = fmaf(w2, bf_lo(u2), ac0);  ac1 = fmaf(w2, bf_hi(u2), ac1);
            ac0 = fmaf(w3, bf_lo(u3), ac0);  ac1 = fmaf(w3, bf_hi(u3), ac1);
            ac0 = fmaf(w4, bf_lo(u4), ac0);  ac1 = fmaf(w4, bf_hi(u4), ac1);
            ac0 = fmaf(w5, bf_lo(u5), ac0);  ac1 = fmaf(w5, bf_hi(u5), ac1);
            ac0 = fmaf(w6, bf_lo(u6), ac0);  ac1 = fmaf(w6, bf_hi(u6), ac1);
            ac0 = fmaf(w7, bf_lo(u7), ac0);  ac1 = fmaf(w7, bf_hi(u7), ac1);
        }
        for (; i < deg; ++i) {
            int c0 = cr[i];
            uint2 q0 = wr[i];
            unsigned x0 = (h & 2) ? q0.y : q0.x;
            float w0 = (h & 1) ? bf_hi(x0) : bf_lo(x0);
            unsigned u0 = xpl[(size_t)c0 * 64];
            ac0 = fmaf(w0, bf_lo(u0), ac0);  ac1 = fmaf(w0, bf_hi(u0), ac1);
        }
    } else {
        const float ash = h == 0 ? as4.x : h == 1 ? as4.y : h == 2 ? as4.z : as4.w;
        for (int i = 0; i < deg; ++i) {
            int c0 = col[start + i];
            float v = ash + a_dst[(size_t)c0 * 4 + h];
            v = v > 0.f ? v : 0.2f * v;
            float w0 = __expf(v);
            unsigned u0 = xpl[(size_t)c0 * 64];
            ac0 = fmaf(w0, bf_lo(u0), ac0);  ac1 = fmaf(w0, bf_hi(u0), ac1);
        }
    }

    if (alive) {
        float2 bv = *(const float2*)(bias + 2 * lane);
        *(float2*)(out + (size_t)n * HC + 2 * lane) =
            make_float2(ac0 * inv + bv.x, ac1 * inv + bv.y);
    }
}

extern "C" void kernel_launch(void* const* d_in, const int* in_sizes, int n_in,
                              void* d_out, int out_size, void* d_ws, size_t ws_size,
                              hipStream_t stream) {
    const float* x       = (const float*)d_in[0];
    const float* weight  = (const float*)d_in[1];
    const float* att_src = (const float*)d_in[2];
    const float* att_dst = (const float*)d_in[3];
    const float* bias    = (const float*)d_in[4];
    const int*   row     = (const int*)d_in[5];
    const int*   col     = (const int*)d_in[6];
    float* out = (float*)d_out;

    const int n_nodes = in_sizes[0] / IN_C;   // 50000
    const int E = in_sizes[5];                // 1.6M

    char* ws = (char*)d_ws;
    unsigned short* xp = (unsigned short*)ws;  ws += (size_t)n_nodes * HC * sizeof(unsigned short);
    float* a_src   = (float*)ws;               ws += (size_t)n_nodes * 4 * sizeof(float);
    float* a_dst   = (float*)ws;               ws += (size_t)n_nodes * 4 * sizeof(float);
    unsigned short* wt = (unsigned short*)ws;  ws += (size_t)IN_C * HC * sizeof(unsigned short);
    int*   row_ptr = (int*)ws;                 ws += (size_t)(n_nodes + 1) * sizeof(int);

    prep_kernel<<<(E + 255) / 256, 256, 0, stream>>>(weight, wt, row, row_ptr, n_nodes, E);
    gemm_kernel<<<(n_nodes + 63) / 64, 256, 0, stream>>>(x, (const uint4*)wt,
                                                         att_src, att_dst,
                                                         xp, a_src, a_dst, n_nodes);
    agg_kernel<<<(n_nodes + 3) / 4, 256, 0, stream>>>((const unsigned*)xp, a_src, a_dst,
                                                      col, row_ptr, bias, out, n_nodes);
}

// Round 13
// 82.574 us; speedup vs baseline: 1.1493x; 1.1493x over previous
//
#include <hip/hip_runtime.h>
#include <hip/hip_bf16.h>

// GATConv: N=50000, E=1.6M (row sorted), IN_C=128, HEADS=4, OUT_C=32 (H*C=128)
//   1) prep_kernel:  W -> Wt (bf16, transposed, swizzled) + row_ptr boundary scatter
//   2) gemm_kernel:  r10-proven: MFMA bf16 16x16x32, 128-row tile (8 waves), LDS
//                    staged A+B, fused att epilogue. (r12's LDS-free variant was
//                    -10us: broadcast B operand belongs in LDS.)
//   3) agg_kernel:   r10 structure; LDS weights stored per-head (4 consecutive bf16)
//                    so phase C reads one ds_read_u16 + shift -- no cndmask selects.
// agg wall (r2-r12): ~171MB random-miss @ ~3.4TB/s; every structural redesign
// (r6 bucket, r7 pool, r8 XCD-slice, r3/r4 width changes) regressed.

#define IN_C 128
#define HC 128
#define STG 256

typedef __attribute__((ext_vector_type(8))) __bf16 bfrag_t;
typedef __attribute__((ext_vector_type(4))) float f32x4;
union frag_u { uint4 u; bfrag_t b; };

static __device__ inline unsigned short f2bf(float f) {
    unsigned u = __float_as_uint(f);
    unsigned r = (u + 0x7fffu + ((u >> 16) & 1u)) >> 16;  // round-nearest-even
    return (unsigned short)r;
}
static __device__ inline unsigned pack2(float a, float b) {
    return (unsigned)f2bf(a) | ((unsigned)f2bf(b) << 16);
}
static __device__ inline float bf_lo(unsigned u) { return __uint_as_float(u << 16); }
static __device__ inline float bf_hi(unsigned u) { return __uint_as_float(u & 0xffff0000u); }
static __device__ inline float bfu(unsigned short s) {
    return __uint_as_float((unsigned)s << 16);
}

__global__ __launch_bounds__(256) void prep_kernel(const float* __restrict__ W,
                                                   unsigned short* __restrict__ wt,
                                                   const int* __restrict__ row,
                                                   int* __restrict__ row_ptr,
                                                   int n_nodes, int E) {
    int gid = blockIdx.x * 256 + threadIdx.x;
    if (gid < IN_C * HC) {
        int n = gid >> 7, k = gid & 127;
        wt[((size_t)n * 16 + ((k >> 3) ^ (n & 7))) * 8 + (k & 7)] =
            f2bf(W[(size_t)k * HC + n]);
    }
    if (gid < E) {
        int lane = threadIdx.x & 63;
        int r1 = row[gid];
        int r0 = __shfl_up(r1, 1, 64);
        if (lane == 0) r0 = (gid == 0) ? -1 : row[gid - 1];
        for (int v = r0 + 1; v <= r1; ++v) row_ptr[v] = gid;
        if (gid == E - 1)
            for (int v = r1 + 1; v <= n_nodes; ++v) row_ptr[v] = E;
    }
}

// r10 MFMA GEMM: block = 128 rows x 128 cols, 8 waves; wave w owns rows 16w..16w+15.
__global__ __launch_bounds__(512) void gemm_kernel(const float* __restrict__ x,
                                                   const uint4* __restrict__ wt,
                                                   const float* __restrict__ attS,
                                                   const float* __restrict__ attD,
                                                   unsigned short* __restrict__ xp,
                                                   float* __restrict__ a_src,
                                                   float* __restrict__ a_dst, int n_nodes) {
    __shared__ uint4 Bl[2048];   // 32KB: Wt (transposed, swizzled)
    __shared__ uint4 Al[2048];   // 32KB: x tile bf16 swizzled: [row][chunk^(row&7)]
    const int tid = threadIdx.x;
    const int base = blockIdx.x * 128;

    #pragma unroll
    for (int i = 0; i < 4; ++i) Bl[tid + 512 * i] = wt[tid + 512 * i];

    #pragma unroll
    for (int i = 0; i < 4; ++i) {
        int idx = tid + 512 * i;
        int row = idx >> 4, chunk = idx & 15;
        uint4 p = make_uint4(0u, 0u, 0u, 0u);
        if (base + row < n_nodes) {
            const float* src = x + (size_t)(base + row) * IN_C + chunk * 8;
            float4 lo = *(const float4*)src;
            float4 hi = *(const float4*)(src + 4);
            p.x = pack2(lo.x, lo.y); p.y = pack2(lo.z, lo.w);
            p.z = pack2(hi.x, hi.y); p.w = pack2(hi.z, hi.w);
        }
        Al[row * 16 + (chunk ^ (row & 7))] = p;
    }
    __syncthreads();

    const int w = tid >> 6, l = tid & 63, l15 = l & 15, q = l >> 4;
    f32x4 acc[8] = {};
    const int arow = 16 * w + l15;
    #pragma unroll
    for (int ks = 0; ks < 4; ++ks) {
        frag_u a; a.u = Al[arow * 16 + ((ks * 4 + q) ^ (arow & 7))];
        #pragma unroll
        for (int t = 0; t < 8; ++t) {
            int brow = 16 * t + l15;
            frag_u b; b.u = Bl[brow * 16 + ((ks * 4 + q) ^ (brow & 7))];
            acc[t] = __builtin_amdgcn_mfma_f32_16x16x32_bf16(a.b, b.b, acc[t], 0, 0, 0);
        }
    }

    // epilogue: xp bf16 stores + att logits (C-frag: col = 16t+l15, row = 16w+4q+r)
    float avS[8], avD[8];
    #pragma unroll
    for (int t = 0; t < 8; ++t) {
        avS[t] = attS[16 * t + l15];
        avD[t] = attD[16 * t + l15];
    }
    float hpS[4][4] = {}, hpD[4][4] = {};
    #pragma unroll
    for (int t = 0; t < 8; ++t) {
        #pragma unroll
        for (int r = 0; r < 4; ++r) {
            float v = acc[t][r];
            hpS[r][t >> 1] = fmaf(v, avS[t], hpS[r][t >> 1]);
            hpD[r][t >> 1] = fmaf(v, avD[t], hpD[r][t >> 1]);
            int grow = base + 16 * w + 4 * q + r;
            if (grow < n_nodes)
                xp[(size_t)grow * HC + 16 * t + l15] = f2bf(v);
        }
    }
    #pragma unroll
    for (int r = 0; r < 4; ++r) {
        #pragma unroll
        for (int h = 0; h < 4; ++h) {
            #pragma unroll
            for (int off = 1; off < 16; off <<= 1) {
                hpS[r][h] += __shfl_xor(hpS[r][h], off, 64);
                hpD[r][h] += __shfl_xor(hpD[r][h], off, 64);
            }
        }
        int grow = base + 16 * w + 4 * q + r;
        if (l15 == 0 && grow < n_nodes) {
            *(float4*)(a_src + (size_t)grow * 4) =
                make_float4(hpS[r][0], hpS[r][1], hpS[r][2], hpS[r][3]);
            *(float4*)(a_dst + (size_t)grow * 4) =
                make_float4(hpD[r][0], hpD[r][1], hpD[r][2], hpD[r][3]);
        }
    }
}

// Aggregation: r10 structure; per-head bf16 LDS weights (scalar u16 read, no selects).
__global__ __launch_bounds__(256, 8) void agg_kernel(const unsigned* __restrict__ xp,
                                                     const float* __restrict__ a_src,
                                                     const float* __restrict__ a_dst,
                                                     const int* __restrict__ col,
                                                     const int* __restrict__ row_ptr,
                                                     const float* __restrict__ bias,
                                                     float* __restrict__ out, int n_nodes) {
    __shared__ unsigned short lds_w[4][STG * 4];  // [edge][head] bf16, 8KB
    __shared__ int lds_c[4][STG];                 // 4KB
    const int wid = threadIdx.x >> 6, lane = threadIdx.x & 63;
    const int n = blockIdx.x * 4 + wid;
    const bool alive = n < n_nodes;

    int start = 0, deg = 0;
    if (alive) { start = row_ptr[n]; deg = row_ptr[n + 1] - start; }
    const bool staged = deg <= STG;
    float4 as4 = alive ? *(const float4*)(a_src + (size_t)n * 4)
                       : make_float4(0.f, 0.f, 0.f, 0.f);

    float s0 = 0.f, s1 = 0.f, s2 = 0.f, s3 = 0.f;
    for (int i = lane; i < deg; i += 64) {
        int cc = col[start + i];
        float4 ad = *(const float4*)(a_dst + (size_t)cc * 4);
        float v0 = as4.x + ad.x, v1 = as4.y + ad.y, v2 = as4.z + ad.z, v3 = as4.w + ad.w;
        v0 = v0 > 0.f ? v0 : 0.2f * v0;  v1 = v1 > 0.f ? v1 : 0.2f * v1;
        v2 = v2 > 0.f ? v2 : 0.2f * v2;  v3 = v3 > 0.f ? v3 : 0.2f * v3;
        float w0 = __expf(v0), w1 = __expf(v1), w2 = __expf(v2), w3 = __expf(v3);
        if (staged) {
            lds_c[wid][i] = cc;
            *(uint2*)&lds_w[wid][i * 4] = make_uint2(pack2(w0, w1), pack2(w2, w3));
        }
        s0 += w0; s1 += w1; s2 += w2; s3 += w3;
    }
    #pragma unroll
    for (int off = 1; off < 64; off <<= 1) {
        s0 += __shfl_xor(s0, off, 64);
        s1 += __shfl_xor(s1, off, 64);
        s2 += __shfl_xor(s2, off, 64);
        s3 += __shfl_xor(s3, off, 64);
    }

    const int h = lane >> 4;
    const float sh = h == 0 ? s0 : h == 1 ? s1 : h == 2 ? s2 : s3;
    const float inv = 1.0f / (sh + 1e-8f);
    const unsigned* xpl = xp + lane;
    float ac0 = 0.f, ac1 = 0.f;

    if (staged) {
        const unsigned short* wr = &lds_w[wid][0];
        const int* cr = &lds_c[wid][0];
        int i = 0;
        for (; i + 8 <= deg; i += 8) {
            int c0 = cr[i+0], c1 = cr[i+1], c2 = cr[i+2], c3 = cr[i+3];
            int c4 = cr[i+4], c5 = cr[i+5], c6 = cr[i+6], c7 = cr[i+7];
            float w0 = bfu(wr[(i+0)*4+h]), w1 = bfu(wr[(i+1)*4+h]);
            float w2 = bfu(wr[(i+2)*4+h]), w3 = bfu(wr[(i+3)*4+h]);
            float w4 = bfu(wr[(i+4)*4+h]), w5 = bfu(wr[(i+5)*4+h]);
            float w6 = bfu(wr[(i+6)*4+h]), w7 = bfu(wr[(i+7)*4+h]);
            unsigned u0 = xpl[(size_t)c0 * 64];
            unsigned u1 = xpl[(size_t)c1 * 64];
            unsigned u2 = xpl[(size_t)c2 * 64];
            unsigned u3 = xpl[(size_t)c3 * 64];
            unsigned u4 = xpl[(size_t)c4 * 64];
            unsigned u5 = xpl[(size_t)c5 * 64];
            unsigned u6 = xpl[(size_t)c6 * 64];
            unsigned u7 = xpl[(size_t)c7 * 64];
            ac0 = fmaf(w0, bf_lo(u0), ac0);  ac1 = fmaf(w0, bf_hi(u0), ac1);
            ac0 = fmaf(w1, bf_lo(u1), ac0);  ac1 = fmaf(w1, bf_hi(u1), ac1);
            ac0 = fmaf(w2, bf_lo(u2), ac0);  ac1 = fmaf(w2, bf_hi(u2), ac1);
            ac0 = fmaf(w3, bf_lo(u3), ac0);  ac1 = fmaf(w3, bf_hi(u3), ac1);
            ac0 = fmaf(w4, bf_lo(u4), ac0);  ac1 = fmaf(w4, bf_hi(u4), ac1);
            ac0 = fmaf(w5, bf_lo(u5), ac0);  ac1 = fmaf(w5, bf_hi(u5), ac1);
            ac0 = fmaf(w6, bf_lo(u6), ac0);  ac1 = fmaf(w6, bf_hi(u6), ac1);
            ac0 = fmaf(w7, bf_lo(u7), ac0);  ac1 = fmaf(w7, bf_hi(u7), ac1);
        }
        for (; i < deg; ++i) {
            int c0 = cr[i];
            float w0 = bfu(wr[i*4+h]);
            unsigned u0 = xpl[(size_t)c0 * 64];
            ac0 = fmaf(w0, bf_lo(u0), ac0);  ac1 = fmaf(w0, bf_hi(u0), ac1);
        }
    } else {
        const float ash = h == 0 ? as4.x : h == 1 ? as4.y : h == 2 ? as4.z : as4.w;
        for (int i = 0; i < deg; ++i) {
            int c0 = col[start + i];
            float v = ash + a_dst[(size_t)c0 * 4 + h];
            v = v > 0.f ? v : 0.2f * v;
            float w0 = __expf(v);
            unsigned u0 = xpl[(size_t)c0 * 64];
            ac0 = fmaf(w0, bf_lo(u0), ac0);  ac1 = fmaf(w0, bf_hi(u0), ac1);
        }
    }

    if (alive) {
        float2 bv = *(const float2*)(bias + 2 * lane);
        *(float2*)(out + (size_t)n * HC + 2 * lane) =
            make_float2(ac0 * inv + bv.x, ac1 * inv + bv.y);
    }
}

extern "C" void kernel_launch(void* const* d_in, const int* in_sizes, int n_in,
                              void* d_out, int out_size, void* d_ws, size_t ws_size,
                              hipStream_t stream) {
    const float* x       = (const float*)d_in[0];
    const float* weight  = (const float*)d_in[1];
    const float* att_src = (const float*)d_in[2];
    const float* att_dst = (const float*)d_in[3];
    const float* bias    = (const float*)d_in[4];
    const int*   row     = (const int*)d_in[5];
    const int*   col     = (const int*)d_in[6];
    float* out = (float*)d_out;

    const int n_nodes = in_sizes[0] / IN_C;   // 50000
    const int E = in_sizes[5];                // 1.6M

    char* ws = (char*)d_ws;
    unsigned short* xp = (unsigned short*)ws;  ws += (size_t)n_nodes * HC * sizeof(unsigned short);
    float* a_src   = (float*)ws;               ws += (size_t)n_nodes * 4 * sizeof(float);
    float* a_dst   = (float*)ws;               ws += (size_t)n_nodes * 4 * sizeof(float);
    unsigned short* wt = (unsigned short*)ws;  ws += (size_t)IN_C * HC * sizeof(unsigned short);
    int*   row_ptr = (int*)ws;                 ws += (size_t)(n_nodes + 1) * sizeof(int);

    prep_kernel<<<(E + 255) / 256, 256, 0, stream>>>(weight, wt, row, row_ptr, n_nodes, E);
    gemm_kernel<<<(n_nodes + 127) / 128, 512, 0, stream>>>(x, (const uint4*)wt,
                                                           att_src, att_dst,
                                                           xp, a_src, a_dst, n_nodes);
    agg_kernel<<<(n_nodes + 3) / 4, 256, 0, stream>>>((const unsigned*)xp, a_src, a_dst,
                                                      col, row_ptr, bias, out, n_nodes);
}

// Round 14
// 78.334 us; speedup vs baseline: 1.2115x; 1.0541x over previous
//
#include <hip/hip_runtime.h>
#include <hip/hip_bf16.h>

// GATConv: N=50000, E=1.6M (row sorted), IN_C=128, HEADS=4, OUT_C=32 (H*C=128)
//   1) prep_kernel:  W -> Wt (bf16, transposed, swizzled, 144 cols: 128 W cols +
//                    8 logit cols WS/WD + 8 zero) + row_ptr boundary scatter.
//                    WS[k][h] = sum_c W[k][h*32+c]*attS[h][c]  (a_src = x @ WS).
//   2) gemm_kernel:  MFMA bf16 16x16x32, 128-row tile, 9 B-tiles: xp cols + logit
//                    cols. Epilogue = scalar stores only (no shuffle reductions).
//   3) agg_kernel:   FROZEN r13: 1 wave/node, max-free softmax, per-head bf16 LDS
//                    weights, full-wave dword gather unroll 8, 8 blocks/CU.
// agg wall (r2-r13): ~172MB random-miss @ ~3.4TB/s; VALU cut (r13: 76->60% busy)
// did not move dur -> memory-pinned. All structural redesigns regressed.

#define IN_C 128
#define HC 128
#define STG 256
#define BCOLS 144   // 128 xp cols + 16 logit-tile cols (8 used, 8 zero)

typedef __attribute__((ext_vector_type(8))) __bf16 bfrag_t;
typedef __attribute__((ext_vector_type(4))) float f32x4;
union frag_u { uint4 u; bfrag_t b; };

static __device__ inline unsigned short f2bf(float f) {
    unsigned u = __float_as_uint(f);
    unsigned r = (u + 0x7fffu + ((u >> 16) & 1u)) >> 16;  // round-nearest-even
    return (unsigned short)r;
}
static __device__ inline unsigned pack2(float a, float b) {
    return (unsigned)f2bf(a) | ((unsigned)f2bf(b) << 16);
}
static __device__ inline float bf_lo(unsigned u) { return __uint_as_float(u << 16); }
static __device__ inline float bf_hi(unsigned u) { return __uint_as_float(u & 0xffff0000u); }
static __device__ inline float bfu(unsigned short s) {
    return __uint_as_float((unsigned)s << 16);
}

// Wt layout: wt[(n*16 + (chunk ^ (n&7)))*8 + (k&7)], chunk = k>>3, n in [0,144).
// n<128: W[k][n]. n=128+h (h<4): WS[k][h]. n=132+h: WD[k][h]. n>=136: 0.
__global__ __launch_bounds__(256) void prep_kernel(const float* __restrict__ W,
                                                   const float* __restrict__ attS,
                                                   const float* __restrict__ attD,
                                                   unsigned short* __restrict__ wt,
                                                   const int* __restrict__ row,
                                                   int* __restrict__ row_ptr,
                                                   int n_nodes, int E) {
    int gid = blockIdx.x * 256 + threadIdx.x;
    if (gid < IN_C * HC) {
        int n = gid >> 7, k = gid & 127;
        wt[((size_t)n * 16 + ((k >> 3) ^ (n & 7))) * 8 + (k & 7)] =
            f2bf(W[(size_t)k * HC + n]);
    } else if (gid < IN_C * HC + 16 * IN_C) {
        int id2 = gid - IN_C * HC;
        int n2 = id2 >> 7, k = id2 & 127;       // n2 in [0,16)
        float v = 0.f;
        if (n2 < 8) {
            int h = n2 & 3;
            const float* wrow = W + (size_t)k * HC + h * 32;
            const float* av = (n2 < 4 ? attS : attD) + h * 32;
            #pragma unroll
            for (int c = 0; c < 32; ++c) v = fmaf(wrow[c], av[c], v);
        }
        int n = 128 + n2;
        wt[((size_t)n * 16 + ((k >> 3) ^ (n & 7))) * 8 + (k & 7)] = f2bf(v);
    }
    if (gid < E) {
        int lane = threadIdx.x & 63;
        int r1 = row[gid];
        int r0 = __shfl_up(r1, 1, 64);
        if (lane == 0) r0 = (gid == 0) ? -1 : row[gid - 1];
        for (int v = r0 + 1; v <= r1; ++v) row_ptr[v] = gid;
        if (gid == E - 1)
            for (int v = r1 + 1; v <= n_nodes; ++v) row_ptr[v] = E;
    }
}

// MFMA GEMM: block = 128 rows x 144 cols, 8 waves; wave w owns rows 16w..16w+15.
__global__ __launch_bounds__(512) void gemm_kernel(const float* __restrict__ x,
                                                   const uint4* __restrict__ wt,
                                                   unsigned short* __restrict__ xp,
                                                   float* __restrict__ a_src,
                                                   float* __restrict__ a_dst, int n_nodes) {
    __shared__ uint4 Bl[BCOLS * 16];  // 36KB: Wt (transposed, swizzled, 144 cols)
    __shared__ uint4 Al[2048];        // 32KB: x tile bf16 swizzled
    const int tid = threadIdx.x;
    const int base = blockIdx.x * 128;

    #pragma unroll
    for (int i = 0; i < 5; ++i) {
        int idx = tid + 512 * i;
        if (idx < BCOLS * 16) Bl[idx] = wt[idx];
    }

    #pragma unroll
    for (int i = 0; i < 4; ++i) {
        int idx = tid + 512 * i;
        int row = idx >> 4, chunk = idx & 15;
        uint4 p = make_uint4(0u, 0u, 0u, 0u);
        if (base + row < n_nodes) {
            const float* src = x + (size_t)(base + row) * IN_C + chunk * 8;
            float4 lo = *(const float4*)src;
            float4 hi = *(const float4*)(src + 4);
            p.x = pack2(lo.x, lo.y); p.y = pack2(lo.z, lo.w);
            p.z = pack2(hi.x, hi.y); p.w = pack2(hi.z, hi.w);
        }
        Al[row * 16 + (chunk ^ (row & 7))] = p;
    }
    __syncthreads();

    const int w = tid >> 6, l = tid & 63, l15 = l & 15, q = l >> 4;
    f32x4 acc[9] = {};
    const int arow = 16 * w + l15;
    #pragma unroll
    for (int ks = 0; ks < 4; ++ks) {
        frag_u a; a.u = Al[arow * 16 + ((ks * 4 + q) ^ (arow & 7))];
        #pragma unroll
        for (int t = 0; t < 9; ++t) {
            int brow = 16 * t + l15;
            frag_u b; b.u = Bl[brow * 16 + ((ks * 4 + q) ^ (brow & 7))];
            acc[t] = __builtin_amdgcn_mfma_f32_16x16x32_bf16(a.b, b.b, acc[t], 0, 0, 0);
        }
    }

    // epilogue: xp bf16 stores (t<8) + direct logit stores from tile t=8.
    // C-frag: col = 16t + l15, row = 16w + 4q + r.
    #pragma unroll
    for (int t = 0; t < 8; ++t) {
        #pragma unroll
        for (int r = 0; r < 4; ++r) {
            int grow = base + 16 * w + 4 * q + r;
            if (grow < n_nodes)
                xp[(size_t)grow * HC + 16 * t + l15] = f2bf(acc[t][r]);
        }
    }
    if (l15 < 8) {
        float* dst = (l15 < 4) ? a_src : a_dst;
        int hh = l15 & 3;
        #pragma unroll
        for (int r = 0; r < 4; ++r) {
            int grow = base + 16 * w + 4 * q + r;
            if (grow < n_nodes) dst[(size_t)grow * 4 + hh] = acc[8][r];
        }
    }
}

// FROZEN r13 aggregation: per-head bf16 LDS weights, 12KB LDS, 8 blocks/CU.
__global__ __launch_bounds__(256, 8) void agg_kernel(const unsigned* __restrict__ xp,
                                                     const float* __restrict__ a_src,
                                                     const float* __restrict__ a_dst,
                                                     const int* __restrict__ col,
                                                     const int* __restrict__ row_ptr,
                                                     const float* __restrict__ bias,
                                                     float* __restrict__ out, int n_nodes) {
    __shared__ unsigned short lds_w[4][STG * 4];
    __shared__ int lds_c[4][STG];
    const int wid = threadIdx.x >> 6, lane = threadIdx.x & 63;
    const int n = blockIdx.x * 4 + wid;
    const bool alive = n < n_nodes;

    int start = 0, deg = 0;
    if (alive) { start = row_ptr[n]; deg = row_ptr[n + 1] - start; }
    const bool staged = deg <= STG;
    float4 as4 = alive ? *(const float4*)(a_src + (size_t)n * 4)
                       : make_float4(0.f, 0.f, 0.f, 0.f);

    float s0 = 0.f, s1 = 0.f, s2 = 0.f, s3 = 0.f;
    for (int i = lane; i < deg; i += 64) {
        int cc = col[start + i];
        float4 ad = *(const float4*)(a_dst + (size_t)cc * 4);
        float v0 = as4.x + ad.x, v1 = as4.y + ad.y, v2 = as4.z + ad.z, v3 = as4.w + ad.w;
        v0 = v0 > 0.f ? v0 : 0.2f * v0;  v1 = v1 > 0.f ? v1 : 0.2f * v1;
        v2 = v2 > 0.f ? v2 : 0.2f * v2;  v3 = v3 > 0.f ? v3 : 0.2f * v3;
        float w0 = __expf(v0), w1 = __expf(v1), w2 = __expf(v2), w3 = __expf(v3);
        if (staged) {
            lds_c[wid][i] = cc;
            *(uint2*)&lds_w[wid][i * 4] = make_uint2(pack2(w0, w1), pack2(w2, w3));
        }
        s0 += w0; s1 += w1; s2 += w2; s3 += w3;
    }
    #pragma unroll
    for (int off = 1; off < 64; off <<= 1) {
        s0 += __shfl_xor(s0, off, 64);
        s1 += __shfl_xor(s1, off, 64);
        s2 += __shfl_xor(s2, off, 64);
        s3 += __shfl_xor(s3, off, 64);
    }

    const int h = lane >> 4;
    const float sh = h == 0 ? s0 : h == 1 ? s1 : h == 2 ? s2 : s3;
    const float inv = 1.0f / (sh + 1e-8f);
    const unsigned* xpl = xp + lane;
    float ac0 = 0.f, ac1 = 0.f;

    if (staged) {
        const unsigned short* wr = &lds_w[wid][0];
        const int* cr = &lds_c[wid][0];
        int i = 0;
        for (; i + 8 <= deg; i += 8) {
            int c0 = cr[i+0], c1 = cr[i+1], c2 = cr[i+2], c3 = cr[i+3];
            int c4 = cr[i+4], c5 = cr[i+5], c6 = cr[i+6], c7 = cr[i+7];
            float w0 = bfu(wr[(i+0)*4+h]), w1 = bfu(wr[(i+1)*4+h]);
            float w2 = bfu(wr[(i+2)*4+h]), w3 = bfu(wr[(i+3)*4+h]);
            float w4 = bfu(wr[(i+4)*4+h]), w5 = bfu(wr[(i+5)*4+h]);
            float w6 = bfu(wr[(i+6)*4+h]), w7 = bfu(wr[(i+7)*4+h]);
            unsigned u0 = xpl[(size_t)c0 * 64];
            unsigned u1 = xpl[(size_t)c1 * 64];
            unsigned u2 = xpl[(size_t)c2 * 64];
            unsigned u3 = xpl[(size_t)c3 * 64];
            unsigned u4 = xpl[(size_t)c4 * 64];
            unsigned u5 = xpl[(size_t)c5 * 64];
            unsigned u6 = xpl[(size_t)c6 * 64];
            unsigned u7 = xpl[(size_t)c7 * 64];
            ac0 = fmaf(w0, bf_lo(u0), ac0);  ac1 = fmaf(w0, bf_hi(u0), ac1);
            ac0 = fmaf(w1, bf_lo(u1), ac0);  ac1 = fmaf(w1, bf_hi(u1), ac1);
            ac0 = fmaf(w2, bf_lo(u2), ac0);  ac1 = fmaf(w2, bf_hi(u2), ac1);
            ac0 = fmaf(w3, bf_lo(u3), ac0);  ac1 = fmaf(w3, bf_hi(u3), ac1);
            ac0 = fmaf(w4, bf_lo(u4), ac0);  ac1 = fmaf(w4, bf_hi(u4), ac1);
            ac0 = fmaf(w5, bf_lo(u5), ac0);  ac1 = fmaf(w5, bf_hi(u5), ac1);
            ac0 = fmaf(w6, bf_lo(u6), ac0);  ac1 = fmaf(w6, bf_hi(u6), ac1);
            ac0 = fmaf(w7, bf_lo(u7), ac0);  ac1 = fmaf(w7, bf_hi(u7), ac1);
        }
        for (; i < deg; ++i) {
            int c0 = cr[i];
            float w0 = bfu(wr[i*4+h]);
            unsigned u0 = xpl[(size_t)c0 * 64];
            ac0 = fmaf(w0, bf_lo(u0), ac0);  ac1 = fmaf(w0, bf_hi(u0), ac1);
        }
    } else {
        const float ash = h == 0 ? as4.x : h == 1 ? as4.y : h == 2 ? as4.z : as4.w;
        for (int i = 0; i < deg; ++i) {
            int c0 = col[start + i];
            float v = ash + a_dst[(size_t)c0 * 4 + h];
            v = v > 0.f ? v : 0.2f * v;
            float w0 = __expf(v);
            unsigned u0 = xpl[(size_t)c0 * 64];
            ac0 = fmaf(w0, bf_lo(u0), ac0);  ac1 = fmaf(w0, bf_hi(u0), ac1);
        }
    }

    if (alive) {
        float2 bv = *(const float2*)(bias + 2 * lane);
        *(float2*)(out + (size_t)n * HC + 2 * lane) =
            make_float2(ac0 * inv + bv.x, ac1 * inv + bv.y);
    }
}

extern "C" void kernel_launch(void* const* d_in, const int* in_sizes, int n_in,
                              void* d_out, int out_size, void* d_ws, size_t ws_size,
                              hipStream_t stream) {
    const float* x       = (const float*)d_in[0];
    const float* weight  = (const float*)d_in[1];
    const float* att_src = (const float*)d_in[2];
    const float* att_dst = (const float*)d_in[3];
    const float* bias    = (const float*)d_in[4];
    const int*   row     = (const int*)d_in[5];
    const int*   col     = (const int*)d_in[6];
    float* out = (float*)d_out;

    const int n_nodes = in_sizes[0] / IN_C;   // 50000
    const int E = in_sizes[5];                // 1.6M

    char* ws = (char*)d_ws;
    unsigned short* xp = (unsigned short*)ws;  ws += (size_t)n_nodes * HC * sizeof(unsigned short);
    float* a_src   = (float*)ws;               ws += (size_t)n_nodes * 4 * sizeof(float);
    float* a_dst   = (float*)ws;               ws += (size_t)n_nodes * 4 * sizeof(float);
    unsigned short* wt = (unsigned short*)ws;  ws += (size_t)BCOLS * IN_C * sizeof(unsigned short);
    int*   row_ptr = (int*)ws;                 ws += (size_t)(n_nodes + 1) * sizeof(int);

    prep_kernel<<<(E + 255) / 256, 256, 0, stream>>>(weight, att_src, att_dst, wt,
                                                     row, row_ptr, n_nodes, E);
    gemm_kernel<<<(n_nodes + 127) / 128, 512, 0, stream>>>(x, (const uint4*)wt,
                                                           xp, a_src, a_dst, n_nodes);
    agg_kernel<<<(n_nodes + 3) / 4, 256, 0, stream>>>((const unsigned*)xp, a_src, a_dst,
                                                      col, row_ptr, bias, out, n_nodes);
}